// Round 9
// baseline (244.994 us; speedup 1.0000x reference)
//
#include <hip/hip_runtime.h>
#include <math.h>

#define NTRI 12288

// ---- workspace layout (float offsets) ----
#define OFF_WT    0u            // 256*1280 ushort: combined (Wk@k_w/Wv@v_w) as B^T [c][k] bf16
#define OFF_PEKV  327680u       // 256*256   folded k/v bias + pe_img      [p][c]
#define OFF_CQWT  393216u       // 64*128 fp32: (Wq@q_w)^T [k][c]
#define OFF_PEQ   401408u       // 12288*128 Wq@(q_b+pe_tri)+bq            [n][c]
#define OFF_W2T   1974272u      // 128*64 fp32: (conv_w@out_w)^T [c][oc]
#define OFF_B2    1982464u      // 64        conv_w@out_b + conv_b
#define OFF_KVPV  2031680u      // 4*5*256*256 ushort bf16: projected k|v volume [b][j][p][c]
#define OFF_GTAB  3342400u      // 4*5*12288*4  packed bilinear params (float4)

typedef short short8 __attribute__((ext_vector_type(8)));
typedef float f32x4 __attribute__((ext_vector_type(4)));

__device__ __forceinline__ unsigned short f2bf(float f) {
  unsigned u = __float_as_uint(f);
  return (unsigned short)((u + 0x7fff + ((u >> 16) & 1)) >> 16);
}
__device__ __forceinline__ float bflo(unsigned u) {
  return __uint_as_float(u << 16);
}
__device__ __forceinline__ float bfhi(unsigned u) {
  return __uint_as_float(u & 0xffff0000u);
}

// merged precompute: [0,1280) comb | [1280,1536) pekv | [1536,1568) cqw |
// [1568,3104) peq | [3104,3137) w2 | [3137,4097) grid
// in_w read directly: inwT[m*384+r] == in_w[r*128+m] (contiguous per thread).
__global__ __launch_bounds__(256) void k_pre(const float* __restrict__ in_w,
    const float* __restrict__ k_w, const float* __restrict__ v_w,
    const float* __restrict__ k_b, const float* __restrict__ v_b,
    const float* __restrict__ in_b, const float* __restrict__ q_w,
    const float* __restrict__ q_b, const float* __restrict__ conv_w,
    const float* __restrict__ out_w, const float* __restrict__ out_b,
    const float* __restrict__ conv_b, const float* __restrict__ proj,
    unsigned short* __restrict__ wTc, float* __restrict__ pekv,
    float* __restrict__ cqwT, float* __restrict__ peq,
    float* __restrict__ w2t, float* __restrict__ b2,
    float4* __restrict__ gtab) {
  __shared__ float spe8[8][128];
  __shared__ float skv[256];
  int bb = blockIdx.x;
  int t = threadIdx.x;

  if (bb < 1280) {
    // comb: wTc[c][i] = bf16( sum_m Wk/Wv[c][m] * (k_w|v_w)[m][i] )
    int i = bb, c = t;
    // stage column i of k_w / v_w into LDS (2 gather loads vs 128 scalar)
    if (t < 128) skv[t] = k_w[(size_t)t * 1280 + i];
    else         skv[t] = v_w[(size_t)(t - 128) * 1280 + i];
    __syncthreads();
    const float* wrow = in_w + (size_t)(128 + c) * 128;
    const float* sp = (c < 128) ? skv : (skv + 128);
    float acc = 0.f;
#pragma unroll 8
    for (int m = 0; m < 128; m += 4) {
      float4 wv = *(const float4*)(wrow + m);
      acc += wv.x * sp[m] + wv.y * sp[m + 1] + wv.z * sp[m + 2] + wv.w * sp[m + 3];
    }
    wTc[(size_t)c * 1280 + i] = f2bf(acc);
  } else if (bb < 1536) {
    // pekv
    int p = bb - 1280;
    if (t < 128) {
      float dv = __expf(-(float)(t & ~1) * (9.210340371976184f / 128.0f));
      float arg = (float)p * dv;
      spe8[0][t] = (t & 1) ? cosf(arg) : sinf(arg);
    }
    __syncthreads();
    const float* bias = (t < 128) ? k_b : v_b;
    const float* wrow = in_w + (size_t)(128 + t) * 128;
    float acc = 0.f;
#pragma unroll 8
    for (int m = 0; m < 128; m += 4) {
      float4 wv = *(const float4*)(wrow + m);
      acc += wv.x * (bias[m] + spe8[0][m]) + wv.y * (bias[m + 1] + spe8[0][m + 1]) +
             wv.z * (bias[m + 2] + spe8[0][m + 2]) + wv.w * (bias[m + 3] + spe8[0][m + 3]);
    }
    pekv[p * 256 + t] = acc + in_b[128 + t];
  } else if (bb < 1568) {
    // cqw: cqwT[k][c] (fp32, validated)
    int idx = (bb - 1536) * 256 + t;  // 8192
    int k = idx >> 7, c = idx & 127;
    const float* wrow = in_w + (size_t)c * 128;
    float acc = 0.f;
#pragma unroll 8
    for (int m = 0; m < 128; m += 4) {
      float4 wv = *(const float4*)(wrow + m);
      acc += wv.x * q_w[m * 64 + k] + wv.y * q_w[(m + 1) * 64 + k] +
             wv.z * q_w[(m + 2) * 64 + k] + wv.w * q_w[(m + 3) * 64 + k];
    }
    cqwT[idx] = acc;
  } else if (bb < 3104) {
    // peq
    int n8 = (bb - 1568) * 8;
    for (int it = 0; it < 4; ++it) {
      int e = it * 256 + t;  // < 1024
      int nn = e >> 7, m = e & 127;
      float dv = __expf(-(float)(m & ~1) * (9.210340371976184f / 128.0f));
      float arg = (float)(n8 + nn) * dv;
      spe8[nn][m] = q_b[m] + ((m & 1) ? cosf(arg) : sinf(arg));
    }
    __syncthreads();
    int c = t & 127, z = t >> 7;
    const float* wrow = in_w + (size_t)c * 128;
    float a0 = 0, a1 = 0, a2 = 0, a3 = 0;
#pragma unroll 4
    for (int m = 0; m < 128; ++m) {
      float w = wrow[m];
      a0 += w * spe8[z * 4 + 0][m];
      a1 += w * spe8[z * 4 + 1][m];
      a2 += w * spe8[z * 4 + 2][m];
      a3 += w * spe8[z * 4 + 3][m];
    }
    float bbv = in_b[c];
    peq[(n8 + z * 4 + 0) * 128 + c] = a0 + bbv;
    peq[(n8 + z * 4 + 1) * 128 + c] = a1 + bbv;
    peq[(n8 + z * 4 + 2) * 128 + c] = a2 + bbv;
    peq[(n8 + z * 4 + 3) * 128 + c] = a3 + bbv;
  } else if (bb < 3137) {
    // w2
    int idx = (bb - 3104) * 256 + t;
    if (idx < 8192) {
      int c = idx >> 6, oc = idx & 63;
      const float* crow = conv_w + oc * 128;
      float acc = 0.f;
      for (int m = 0; m < 128; ++m)
        acc += crow[m] * out_w[m * 128 + c];
      w2t[c * 64 + oc] = acc;
    } else if (idx < 8256) {
      int oc = idx - 8192;
      float acc = 0.f;
      for (int m = 0; m < 128; ++m)
        acc += conv_w[oc * 128 + m] * out_b[m];
      b2[oc] = acc + conv_b[oc];
    }
  } else {
    // grid
    int idx = (bb - 3137) * 256 + t;  // 245760
    int n = idx % NTRI;
    int bj = idx / NTRI;
    int plane = n >> 12, rem = n & 4095;
    float fa = (float)(rem & 63), fb = (float)(rem >> 6);
    float cx, cy, cz;
    if (plane == 0)      { cx = fa;    cy = 31.5f; cz = fb; }
    else if (plane == 1) { cx = fa;    cy = fb;    cz = 31.5f; }
    else                 { cx = 31.5f; cy = fa;    cz = fb; }
    const float s2 = 2.20002f;
    cx = (cx / 63.0f - 0.5f) * s2;
    cy = (cy / 63.0f - 0.5f) * s2;
    cz = (cz / 63.0f - 0.5f) * s2;
    const float* P = &proj[bj * 16];
    float d0 = cx * P[0] + cy * P[1] + cz * P[2] + P[3];
    float d1 = cx * P[4] + cy * P[5] + cz * P[6] + P[7];
    float d2 = cx * P[8] + cy * P[9] + cz * P[10] + P[11];
    float x = d0 / d2 / 223.0f;
    float y = d1 / d2 / 223.0f;
    float gx = fminf(fmaxf((x - 0.5f) * 2.0f, -1.0f), 1.0f);
    float gy = fminf(fmaxf((y - 0.5f) * 2.0f, -1.0f), 1.0f);
    float ix = (gx + 1.0f) * 7.5f, iy = (gy + 1.0f) * 7.5f;
    float fx = floorf(ix), fy = floorf(iy);
    float wx = ix - fx, wy = iy - fy;
    int x0 = (int)fx; x0 = x0 < 0 ? 0 : (x0 > 15 ? 15 : x0);
    int y0 = (int)fy; y0 = y0 < 0 ? 0 : (y0 > 15 ? 15 : y0);
    int x1 = x0 + 1 > 15 ? 15 : x0 + 1;
    int y1 = y0 + 1 > 15 ? 15 : y0 + 1;
    int pack = x0 | (x1 << 8) | (y0 << 16) | (y1 << 24);
    gtab[idx] = make_float4(wx, wy, __int_as_float(pack), 0.f);
  }
}

// kvpv MFMA GEMM: C[5120][256] = imgrows(bf16) @ wTc^T + pekv, stored bf16.
// 32x64 tile per block, 640 blocks, 4 waves, register prefetch of tile k+1.
#define LDA 72
__global__ __launch_bounds__(256) void k_kv(const float* __restrict__ img,
    const unsigned short* __restrict__ wTc, const float* __restrict__ pekv,
    unsigned short* __restrict__ kv16) {
  __shared__ unsigned short sA[32 * LDA];
  __shared__ unsigned short sB[64 * LDA];
  int t = threadIdx.x;
  int gm = blockIdx.x >> 2;  // 0..159 (32-row tile)
  int gn = blockIdx.x & 3;   // 0..3
  int r0 = gm * 32, c0 = gn * 64;
  int lane = t & 63, w = t >> 6;
  int wm = w & 1, wn = w >> 1;
  int lrow = lane & 15, quad = lane >> 4;
  int srow = t >> 3, schunk = t & 7;   // staging: 16B chunk per thread
  int bj = gm >> 3;                    // uniform per block (32 | 256)
  f32x4 acc0 = {0,0,0,0}, acc1 = {0,0,0,0};

  float4 pA0, pA1;
  short8 pB0, pB1;
  auto issue = [&](int kt) {
    int k0 = kt * 64;
    const float4* s = (const float4*)&img[(size_t)(r0 + srow + bj + 1) * 1280 + k0 + schunk * 8];
    pA0 = s[0]; pA1 = s[1];
    pB0 = *(const short8*)&wTc[(size_t)(c0 + srow) * 1280 + k0 + schunk * 8];
    pB1 = *(const short8*)&wTc[(size_t)(c0 + srow + 32) * 1280 + k0 + schunk * 8];
  };
  issue(0);

  for (int kt = 0; kt < 20; ++kt) {
    __syncthreads();
    {
      short8 av;
      av[0] = (short)f2bf(pA0.x); av[1] = (short)f2bf(pA0.y);
      av[2] = (short)f2bf(pA0.z); av[3] = (short)f2bf(pA0.w);
      av[4] = (short)f2bf(pA1.x); av[5] = (short)f2bf(pA1.y);
      av[6] = (short)f2bf(pA1.z); av[7] = (short)f2bf(pA1.w);
      *(short8*)&sA[srow * LDA + schunk * 8] = av;
      *(short8*)&sB[srow * LDA + schunk * 8] = pB0;
      *(short8*)&sB[(srow + 32) * LDA + schunk * 8] = pB1;
    }
    __syncthreads();
    if (kt < 19) issue(kt + 1);  // in flight over the MFMA section
#pragma unroll
    for (int kk = 0; kk < 2; ++kk) {
      int kof = kk * 32 + quad * 8;
      short8 a  = *(const short8*)&sA[(wm * 16 + lrow) * LDA + kof];
      short8 b0 = *(const short8*)&sB[(wn * 32 + lrow) * LDA + kof];
      short8 b1 = *(const short8*)&sB[(wn * 32 + 16 + lrow) * LDA + kof];
      acc0 = __builtin_amdgcn_mfma_f32_16x16x32_bf16(a, b0, acc0, 0, 0, 0);
      acc1 = __builtin_amdgcn_mfma_f32_16x16x32_bf16(a, b1, acc1, 0, 0, 0);
    }
  }
  f32x4 accs[2] = {acc0, acc1};
#pragma unroll
  for (int ni = 0; ni < 2; ++ni)
#pragma unroll
    for (int r = 0; r < 4; ++r) {
      int grow = r0 + wm * 16 + quad * 4 + r;
      int gcol = c0 + wn * 32 + ni * 16 + lrow;
      kv16[(size_t)grow * 256 + gcol] =
          f2bf(accs[ni][r] + pekv[(grow & 255) * 256 + gcol]);
    }
}

// fused: scalar fp32 qp GEMM -> bf16 gather/lerp attention -> fp32 out-proj.
// (byte-identical to round 8)
__global__ __launch_bounds__(256, 2) void k_main(const float* __restrict__ tri,
    const float* __restrict__ cqwT, const float* __restrict__ peq,
    const float* __restrict__ w2t, const float* __restrict__ b2,
    const unsigned short* __restrict__ kv16, const float4* __restrict__ gtab,
    float* __restrict__ outp) {
  __shared__ float sQP[32 * 132];   // qp fp32 [pt][c]; later FO[oc][pt] @33
  __shared__ float sBuf[32 * 132];  // phases 1-2: tq [k][pt]@36 ; 3+: O [pt][c]@132
  float* sTQ = sBuf;
  float* sO2 = sBuf;
  int t = threadIdx.x;
  int lane = t & 63, w = t >> 6;
  int b = blockIdx.x / 384;
  int n0 = (blockIdx.x % 384) * 32;

  // phase 1: stage tq fp32 -> LDS [k][pt]
  for (int it = 0; it < 8; ++it) {
    int e = it * 256 + t;
    int k = e >> 5, pt = e & 31;
    sTQ[k * 36 + pt] = tri[(size_t)(b * 64 + k) * NTRI + n0 + pt];
  }
  __syncthreads();

  // phase 2: QP[pt][c] = tq @ cqwT + peq, scalar fp32 (validated)
  {
    int c4 = (t & 31) * 4;
    int p4 = (t >> 5) * 4;
    const float* cw = cqwT + c4;
    float4 A0 = {0,0,0,0}, A1 = {0,0,0,0}, A2 = {0,0,0,0}, A3 = {0,0,0,0};
#pragma unroll 4
    for (int k = 0; k < 64; ++k) {
      float4 wv = *(const float4*)(cw + k * 128);
      float4 aq = *(const float4*)&sTQ[k * 36 + p4];
      A0.x += aq.x * wv.x; A0.y += aq.x * wv.y; A0.z += aq.x * wv.z; A0.w += aq.x * wv.w;
      A1.x += aq.y * wv.x; A1.y += aq.y * wv.y; A1.z += aq.y * wv.z; A1.w += aq.y * wv.w;
      A2.x += aq.z * wv.x; A2.y += aq.z * wv.y; A2.z += aq.z * wv.z; A2.w += aq.z * wv.w;
      A3.x += aq.w * wv.x; A3.y += aq.w * wv.y; A3.z += aq.w * wv.z; A3.w += aq.w * wv.w;
    }
    float4 acc[4] = {A0, A1, A2, A3};
#pragma unroll
    for (int pp = 0; pp < 4; ++pp) {
      float4 pe = *(const float4*)&peq[(size_t)(n0 + p4 + pp) * 128 + c4];
      float4 r;
      r.x = acc[pp].x + pe.x; r.y = acc[pp].y + pe.y;
      r.z = acc[pp].z + pe.z; r.w = acc[pp].w + pe.w;
      *(float4*)&sQP[(p4 + pp) * 132 + c4] = r;
    }
  }
  __syncthreads();

  // phase 3: attention. 32 lanes per point, 4 channels per lane. bf16 kv.
  {
    int sub = lane & 31, half = lane >> 5, c4 = sub * 4;
    const unsigned short* Vb = kv16 + (size_t)b * 5 * 65536;
    const float4* gbase = &gtab[(size_t)(b * 5) * NTRI];
    for (int s = 0; s < 4; ++s) {
      int pt = s * 8 + w * 2 + half;
      int n = n0 + pt;
      float4 qp4 = *(const float4*)&sQP[pt * 132 + c4];
      float4 gp[5];
#pragma unroll
      for (int j = 0; j < 5; ++j) gp[j] = gbase[(size_t)j * NTRI + n];
      float4 vst[5];
      float sc[5];
#pragma unroll
      for (int j = 0; j < 5; ++j) {
        int pack = __float_as_int(gp[j].z);
        int x0 = pack & 255, x1 = (pack >> 8) & 255;
        int y0 = (pack >> 16) & 255, y1 = (pack >> 24) & 255;
        float wx = gp[j].x, wy = gp[j].y;
        const unsigned short* r0 = Vb + j * 65536 + y0 * 4096;
        const unsigned short* r1 = Vb + j * 65536 + y1 * 4096;
        int i0 = x0 * 256 + c4, i1 = x1 * 256 + c4;
        uint2 K00 = *(const uint2*)(r0 + i0), K01 = *(const uint2*)(r0 + i1);
        uint2 K10 = *(const uint2*)(r1 + i0), K11 = *(const uint2*)(r1 + i1);
        uint2 V00 = *(const uint2*)(r0 + i0 + 128), V01 = *(const uint2*)(r0 + i1 + 128);
        uint2 V10 = *(const uint2*)(r1 + i0 + 128), V11 = *(const uint2*)(r1 + i1 + 128);
        float w00 = (1.f - wx) * (1.f - wy), w01 = wx * (1.f - wy);
        float w10 = (1.f - wx) * wy, w11 = wx * wy;
        float4 kc, vc;
        kc.x = bflo(K00.x) * w00 + bflo(K01.x) * w01 + bflo(K10.x) * w10 + bflo(K11.x) * w11;
        kc.y = bfhi(K00.x) * w00 + bfhi(K01.x) * w01 + bfhi(K10.x) * w10 + bfhi(K11.x) * w11;
        kc.z = bflo(K00.y) * w00 + bflo(K01.y) * w01 + bflo(K10.y) * w10 + bflo(K11.y) * w11;
        kc.w = bfhi(K00.y) * w00 + bfhi(K01.y) * w01 + bfhi(K10.y) * w10 + bfhi(K11.y) * w11;
        vc.x = bflo(V00.x) * w00 + bflo(V01.x) * w01 + bflo(V10.x) * w10 + bflo(V11.x) * w11;
        vc.y = bfhi(V00.x) * w00 + bfhi(V01.x) * w01 + bfhi(V10.x) * w10 + bfhi(V11.x) * w11;
        vc.z = bflo(V00.y) * w00 + bflo(V01.y) * w01 + bflo(V10.y) * w10 + bflo(V11.y) * w11;
        vc.w = bfhi(V00.y) * w00 + bfhi(V01.y) * w01 + bfhi(V10.y) * w10 + bfhi(V11.y) * w11;
        vst[j] = vc;
        float pa = qp4.x * kc.x + qp4.y * kc.y + qp4.z * kc.z + qp4.w * kc.w;
        pa += __shfl_xor(pa, 1);
        pa += __shfl_xor(pa, 2);   // head = 16 ch = 4 lanes
        sc[j] = pa * 0.25f;
      }
      float mx = fmaxf(fmaxf(fmaxf(sc[0], sc[1]), fmaxf(sc[2], sc[3])), sc[4]);
      float e0 = expf(sc[0] - mx), e1 = expf(sc[1] - mx), e2 = expf(sc[2] - mx);
      float e3 = expf(sc[3] - mx), e4 = expf(sc[4] - mx);
      float inv = 1.0f / (e0 + e1 + e2 + e3 + e4);
      float4 oa;
      oa.x = (e0 * vst[0].x + e1 * vst[1].x + e2 * vst[2].x + e3 * vst[3].x + e4 * vst[4].x) * inv;
      oa.y = (e0 * vst[0].y + e1 * vst[1].y + e2 * vst[2].y + e3 * vst[3].y + e4 * vst[4].y) * inv;
      oa.z = (e0 * vst[0].z + e1 * vst[1].z + e2 * vst[2].z + e3 * vst[3].z + e4 * vst[4].z) * inv;
      oa.w = (e0 * vst[0].w + e1 * vst[1].w + e2 * vst[2].w + e3 * vst[3].w + e4 * vst[4].w) * inv;
      *(float4*)&sO2[pt * 132 + c4] = oa;
    }
  }
  __syncthreads();

  // phase 4: FO[oc][pt] = W2 @ O + b2 (fp32 VALU)
  {
    int oc4 = (t & 15) * 4;
    int pg = t >> 4;  // 16 groups x 2 pts
    float f00 = 0, f01 = 0, f02 = 0, f03 = 0;
    float f10 = 0, f11 = 0, f12 = 0, f13 = 0;
    const float* o0 = &sO2[(pg * 2) * 132];
    const float* o1 = &sO2[(pg * 2 + 1) * 132];
#pragma unroll 8
    for (int cc = 0; cc < 128; ++cc) {
      float4 wv = *(const float4*)&w2t[cc * 64 + oc4];
      float ax = o0[cc], ay = o1[cc];
      f00 += ax * wv.x; f01 += ax * wv.y; f02 += ax * wv.z; f03 += ax * wv.w;
      f10 += ay * wv.x; f11 += ay * wv.y; f12 += ay * wv.z; f13 += ay * wv.w;
    }
    float4 bb = *(const float4*)&b2[oc4];
    int p0 = pg * 2, p1 = pg * 2 + 1;
    sQP[(oc4 + 0) * 33 + p0] = f00 + bb.x; sQP[(oc4 + 0) * 33 + p1] = f10 + bb.x;
    sQP[(oc4 + 1) * 33 + p0] = f01 + bb.y; sQP[(oc4 + 1) * 33 + p1] = f11 + bb.y;
    sQP[(oc4 + 2) * 33 + p0] = f02 + bb.z; sQP[(oc4 + 2) * 33 + p1] = f12 + bb.z;
    sQP[(oc4 + 3) * 33 + p0] = f03 + bb.w; sQP[(oc4 + 3) * 33 + p1] = f13 + bb.w;
  }
  __syncthreads();

  for (int it = 0; it < 8; ++it) {
    int e = it * 256 + t;
    int oc = e >> 5, pt = e & 31;
    outp[(size_t)(b * 64 + oc) * NTRI + n0 + pt] = sQP[oc * 33 + pt];
  }
}

extern "C" void kernel_launch(void* const* d_in, const int* in_sizes, int n_in,
                              void* d_out, int out_size, void* d_ws, size_t ws_size,
                              hipStream_t stream) {
  const float* tri    = (const float*)d_in[0];
  const float* img    = (const float*)d_in[1];
  const float* proj   = (const float*)d_in[2];
  const float* k_w    = (const float*)d_in[4];
  const float* k_b    = (const float*)d_in[5];
  const float* q_w    = (const float*)d_in[6];
  const float* q_b    = (const float*)d_in[7];
  const float* v_w    = (const float*)d_in[8];
  const float* v_b    = (const float*)d_in[9];
  const float* in_w   = (const float*)d_in[10];
  const float* in_b   = (const float*)d_in[11];
  const float* out_w  = (const float*)d_in[12];
  const float* out_b  = (const float*)d_in[13];
  const float* conv_w = (const float*)d_in[14];
  const float* conv_b = (const float*)d_in[15];
  float* ws = (float*)d_ws;
  unsigned short* wTc  = (unsigned short*)(ws + OFF_WT);
  float* pekv = ws + OFF_PEKV;
  float* cqwT = ws + OFF_CQWT;
  float* peq  = ws + OFF_PEQ;
  float* w2t  = ws + OFF_W2T;
  float* b2   = ws + OFF_B2;
  unsigned short* kv16 = (unsigned short*)(ws + OFF_KVPV);
  float* gtab = ws + OFF_GTAB;
  float* outp = (float*)d_out;

  k_pre<<<4097, 256, 0, stream>>>(in_w, k_w, v_w, k_b, v_b, in_b, q_w, q_b,
                                  conv_w, out_w, out_b, conv_b, proj,
                                  wTc, pekv, cqwT, peq, w2t, b2, (float4*)gtab);
  k_kv<<<640, 256, 0, stream>>>(img, wTc, pekv, kv16);
  k_main<<<1536, 256, 0, stream>>>(tri, cqwT, peq, w2t, b2, kv16,
                                   (const float4*)gtab, outp);
}

// Round 10
// 217.645 us; speedup vs baseline: 1.1257x; 1.1257x over previous
//
#include <hip/hip_runtime.h>
#include <math.h>

#define NTRI 12288

// ---- workspace layout (float offsets) ----
#define OFF_WT    0u            // 256*1280 ushort: combined (Wk@k_w/Wv@v_w) as B^T [c][k] bf16
#define OFF_PEKV  327680u       // 256*256   folded k/v bias + pe_img      [p][c]
#define OFF_CQWT  393216u       // 64*128 fp32: (Wq@q_w)^T [k][c]
#define OFF_PEQ   401408u       // 12288*128 Wq@(q_b+pe_tri)+bq            [n][c]
#define OFF_W2T   1974272u      // 128*64 fp32: (conv_w@out_w)^T [c][oc]
#define OFF_B2    1982464u      // 64        conv_w@out_b + conv_b
#define OFF_INWT  1982528u      // 128*384   in_w transposed               [m][r]
#define OFF_KVPV  2031680u      // 4*5*256*256 ushort bf16: projected k|v volume [b][j][p][c]
#define OFF_GTAB  3342400u      // 4*5*12288*4  packed bilinear params (float4)

typedef short short8 __attribute__((ext_vector_type(8)));
typedef float f32x4 __attribute__((ext_vector_type(4)));

__device__ __forceinline__ unsigned short f2bf(float f) {
  unsigned u = __float_as_uint(f);
  return (unsigned short)((u + 0x7fff + ((u >> 16) & 1)) >> 16);
}
__device__ __forceinline__ float bflo(unsigned u) {
  return __uint_as_float(u << 16);
}
__device__ __forceinline__ float bfhi(unsigned u) {
  return __uint_as_float(u & 0xffff0000u);
}

// transpose in_w -> inwT[m][r]: lane-coalesced reads in k_pre's inner loops
// (consecutive c across lanes = consecutive addresses; round-9's direct
// in_w row reads were 512B-strided across lanes -> 8x transaction inflation)
__global__ __launch_bounds__(256) void k_inwT(const float* __restrict__ in_w,
                                              float* __restrict__ inwT) {
  int idx = blockIdx.x * 256 + threadIdx.x;  // 49152
  int r = idx >> 7, m = idx & 127;
  inwT[m * 384 + r] = in_w[idx];
}

// merged precompute: [0,1280) comb | [1280,1536) pekv | [1536,1568) cqw |
// [1568,3104) peq | [3104,3137) w2 | [3137,4097) grid
__global__ __launch_bounds__(256) void k_pre(const float* __restrict__ inwT,
    const float* __restrict__ k_w, const float* __restrict__ v_w,
    const float* __restrict__ k_b, const float* __restrict__ v_b,
    const float* __restrict__ in_b, const float* __restrict__ q_w,
    const float* __restrict__ q_b, const float* __restrict__ conv_w,
    const float* __restrict__ out_w, const float* __restrict__ out_b,
    const float* __restrict__ conv_b, const float* __restrict__ proj,
    unsigned short* __restrict__ wTc, float* __restrict__ pekv,
    float* __restrict__ cqwT, float* __restrict__ peq,
    float* __restrict__ w2t, float* __restrict__ b2,
    float4* __restrict__ gtab) {
  __shared__ float spe8[8][128];
  __shared__ float skv[256];
  int bb = blockIdx.x;
  int t = threadIdx.x;

  if (bb < 1280) {
    // comb: wTc[c][i] = bf16( sum_m Wk/Wv[c][m] * (k_w|v_w)[m][i] )
    int i = bb, c = t;
    if (t < 128) skv[t] = k_w[(size_t)t * 1280 + i];
    else         skv[t] = v_w[(size_t)(t - 128) * 1280 + i];
    __syncthreads();
    const float* sp = (c < 128) ? skv : (skv + 128);
    float acc = 0.f;
    for (int m = 0; m < 128; ++m)
      acc += inwT[m * 384 + 128 + c] * sp[m];
    wTc[(size_t)c * 1280 + i] = f2bf(acc);
  } else if (bb < 1536) {
    // pekv
    int p = bb - 1280;
    if (t < 128) {
      float dv = __expf(-(float)(t & ~1) * (9.210340371976184f / 128.0f));
      float arg = (float)p * dv;
      spe8[0][t] = (t & 1) ? cosf(arg) : sinf(arg);
    }
    __syncthreads();
    const float* bias = (t < 128) ? k_b : v_b;
    float acc = 0.f;
    for (int m = 0; m < 128; ++m)
      acc += inwT[m * 384 + 128 + t] * (bias[m] + spe8[0][m]);
    pekv[p * 256 + t] = acc + in_b[128 + t];
  } else if (bb < 1568) {
    // cqw: cqwT[k][c] (fp32, validated)
    int idx = (bb - 1536) * 256 + t;  // 8192
    int k = idx >> 7, c = idx & 127;
    float acc = 0.f;
    for (int m = 0; m < 128; ++m)
      acc += inwT[m * 384 + c] * q_w[m * 64 + k];
    cqwT[idx] = acc;
  } else if (bb < 3104) {
    // peq
    int n8 = (bb - 1568) * 8;
    for (int it = 0; it < 4; ++it) {
      int e = it * 256 + t;  // < 1024
      int nn = e >> 7, m = e & 127;
      float dv = __expf(-(float)(m & ~1) * (9.210340371976184f / 128.0f));
      float arg = (float)(n8 + nn) * dv;
      spe8[nn][m] = q_b[m] + ((m & 1) ? cosf(arg) : sinf(arg));
    }
    __syncthreads();
    int c = t & 127, z = t >> 7;
    float a0 = 0, a1 = 0, a2 = 0, a3 = 0;
    for (int m = 0; m < 128; ++m) {
      float w = inwT[m * 384 + c];
      a0 += w * spe8[z * 4 + 0][m];
      a1 += w * spe8[z * 4 + 1][m];
      a2 += w * spe8[z * 4 + 2][m];
      a3 += w * spe8[z * 4 + 3][m];
    }
    float bbv = in_b[c];
    peq[(n8 + z * 4 + 0) * 128 + c] = a0 + bbv;
    peq[(n8 + z * 4 + 1) * 128 + c] = a1 + bbv;
    peq[(n8 + z * 4 + 2) * 128 + c] = a2 + bbv;
    peq[(n8 + z * 4 + 3) * 128 + c] = a3 + bbv;
  } else if (bb < 3137) {
    // w2
    int idx = (bb - 3104) * 256 + t;
    if (idx < 8192) {
      int c = idx >> 6, oc = idx & 63;
      float acc = 0.f;
      for (int m = 0; m < 128; ++m)
        acc += conv_w[oc * 128 + m] * out_w[m * 128 + c];
      w2t[c * 64 + oc] = acc;
    } else if (idx < 8256) {
      int oc = idx - 8192;
      float acc = 0.f;
      for (int m = 0; m < 128; ++m)
        acc += conv_w[oc * 128 + m] * out_b[m];
      b2[oc] = acc + conv_b[oc];
    }
  } else {
    // grid
    int idx = (bb - 3137) * 256 + t;  // 245760
    int n = idx % NTRI;
    int bj = idx / NTRI;
    int plane = n >> 12, rem = n & 4095;
    float fa = (float)(rem & 63), fb = (float)(rem >> 6);
    float cx, cy, cz;
    if (plane == 0)      { cx = fa;    cy = 31.5f; cz = fb; }
    else if (plane == 1) { cx = fa;    cy = fb;    cz = 31.5f; }
    else                 { cx = 31.5f; cy = fa;    cz = fb; }
    const float s2 = 2.20002f;
    cx = (cx / 63.0f - 0.5f) * s2;
    cy = (cy / 63.0f - 0.5f) * s2;
    cz = (cz / 63.0f - 0.5f) * s2;
    const float* P = &proj[bj * 16];
    float d0 = cx * P[0] + cy * P[1] + cz * P[2] + P[3];
    float d1 = cx * P[4] + cy * P[5] + cz * P[6] + P[7];
    float d2 = cx * P[8] + cy * P[9] + cz * P[10] + P[11];
    float x = d0 / d2 / 223.0f;
    float y = d1 / d2 / 223.0f;
    float gx = fminf(fmaxf((x - 0.5f) * 2.0f, -1.0f), 1.0f);
    float gy = fminf(fmaxf((y - 0.5f) * 2.0f, -1.0f), 1.0f);
    float ix = (gx + 1.0f) * 7.5f, iy = (gy + 1.0f) * 7.5f;
    float fx = floorf(ix), fy = floorf(iy);
    float wx = ix - fx, wy = iy - fy;
    int x0 = (int)fx; x0 = x0 < 0 ? 0 : (x0 > 15 ? 15 : x0);
    int y0 = (int)fy; y0 = y0 < 0 ? 0 : (y0 > 15 ? 15 : y0);
    int x1 = x0 + 1 > 15 ? 15 : x0 + 1;
    int y1 = y0 + 1 > 15 ? 15 : y0 + 1;
    int pack = x0 | (x1 << 8) | (y0 << 16) | (y1 << 24);
    gtab[idx] = make_float4(wx, wy, __int_as_float(pack), 0.f);
  }
}

// kvpv MFMA GEMM: C[5120][256] = imgrows(bf16) @ wTc^T + pekv, stored bf16.
// 32x64 tile per block, 640 blocks, 4 waves, register prefetch of tile k+1.
#define LDA 72
__global__ __launch_bounds__(256) void k_kv(const float* __restrict__ img,
    const unsigned short* __restrict__ wTc, const float* __restrict__ pekv,
    unsigned short* __restrict__ kv16) {
  __shared__ unsigned short sA[32 * LDA];
  __shared__ unsigned short sB[64 * LDA];
  int t = threadIdx.x;
  int gm = blockIdx.x >> 2;  // 0..159 (32-row tile)
  int gn = blockIdx.x & 3;   // 0..3
  int r0 = gm * 32, c0 = gn * 64;
  int lane = t & 63, w = t >> 6;
  int wm = w & 1, wn = w >> 1;
  int lrow = lane & 15, quad = lane >> 4;
  int srow = t >> 3, schunk = t & 7;   // staging: 16B chunk per thread
  int bj = gm >> 3;                    // uniform per block (32 | 256)
  f32x4 acc0 = {0,0,0,0}, acc1 = {0,0,0,0};

  float4 pA0, pA1;
  short8 pB0, pB1;
  auto issue = [&](int kt) {
    int k0 = kt * 64;
    const float4* s = (const float4*)&img[(size_t)(r0 + srow + bj + 1) * 1280 + k0 + schunk * 8];
    pA0 = s[0]; pA1 = s[1];
    pB0 = *(const short8*)&wTc[(size_t)(c0 + srow) * 1280 + k0 + schunk * 8];
    pB1 = *(const short8*)&wTc[(size_t)(c0 + srow + 32) * 1280 + k0 + schunk * 8];
  };
  issue(0);

  for (int kt = 0; kt < 20; ++kt) {
    __syncthreads();
    {
      short8 av;
      av[0] = (short)f2bf(pA0.x); av[1] = (short)f2bf(pA0.y);
      av[2] = (short)f2bf(pA0.z); av[3] = (short)f2bf(pA0.w);
      av[4] = (short)f2bf(pA1.x); av[5] = (short)f2bf(pA1.y);
      av[6] = (short)f2bf(pA1.z); av[7] = (short)f2bf(pA1.w);
      *(short8*)&sA[srow * LDA + schunk * 8] = av;
      *(short8*)&sB[srow * LDA + schunk * 8] = pB0;
      *(short8*)&sB[(srow + 32) * LDA + schunk * 8] = pB1;
    }
    __syncthreads();
    if (kt < 19) issue(kt + 1);  // in flight over the MFMA section
#pragma unroll
    for (int kk = 0; kk < 2; ++kk) {
      int kof = kk * 32 + quad * 8;
      short8 a  = *(const short8*)&sA[(wm * 16 + lrow) * LDA + kof];
      short8 b0 = *(const short8*)&sB[(wn * 32 + lrow) * LDA + kof];
      short8 b1 = *(const short8*)&sB[(wn * 32 + 16 + lrow) * LDA + kof];
      acc0 = __builtin_amdgcn_mfma_f32_16x16x32_bf16(a, b0, acc0, 0, 0, 0);
      acc1 = __builtin_amdgcn_mfma_f32_16x16x32_bf16(a, b1, acc1, 0, 0, 0);
    }
  }
  f32x4 accs[2] = {acc0, acc1};
#pragma unroll
  for (int ni = 0; ni < 2; ++ni)
#pragma unroll
    for (int r = 0; r < 4; ++r) {
      int grow = r0 + wm * 16 + quad * 4 + r;
      int gcol = c0 + wn * 32 + ni * 16 + lrow;
      kv16[(size_t)grow * 256 + gcol] =
          f2bf(accs[ni][r] + pekv[(grow & 255) * 256 + gcol]);
    }
}

// fused: scalar fp32 qp GEMM -> bf16 gather/lerp attention -> fp32 out-proj.
// (byte-identical to rounds 8/9)
__global__ __launch_bounds__(256, 2) void k_main(const float* __restrict__ tri,
    const float* __restrict__ cqwT, const float* __restrict__ peq,
    const float* __restrict__ w2t, const float* __restrict__ b2,
    const unsigned short* __restrict__ kv16, const float4* __restrict__ gtab,
    float* __restrict__ outp) {
  __shared__ float sQP[32 * 132];   // qp fp32 [pt][c]; later FO[oc][pt] @33
  __shared__ float sBuf[32 * 132];  // phases 1-2: tq [k][pt]@36 ; 3+: O [pt][c]@132
  float* sTQ = sBuf;
  float* sO2 = sBuf;
  int t = threadIdx.x;
  int lane = t & 63, w = t >> 6;
  int b = blockIdx.x / 384;
  int n0 = (blockIdx.x % 384) * 32;

  // phase 1: stage tq fp32 -> LDS [k][pt]
  for (int it = 0; it < 8; ++it) {
    int e = it * 256 + t;
    int k = e >> 5, pt = e & 31;
    sTQ[k * 36 + pt] = tri[(size_t)(b * 64 + k) * NTRI + n0 + pt];
  }
  __syncthreads();

  // phase 2: QP[pt][c] = tq @ cqwT + peq, scalar fp32 (validated)
  {
    int c4 = (t & 31) * 4;
    int p4 = (t >> 5) * 4;
    const float* cw = cqwT + c4;
    float4 A0 = {0,0,0,0}, A1 = {0,0,0,0}, A2 = {0,0,0,0}, A3 = {0,0,0,0};
#pragma unroll 4
    for (int k = 0; k < 64; ++k) {
      float4 wv = *(const float4*)(cw + k * 128);
      float4 aq = *(const float4*)&sTQ[k * 36 + p4];
      A0.x += aq.x * wv.x; A0.y += aq.x * wv.y; A0.z += aq.x * wv.z; A0.w += aq.x * wv.w;
      A1.x += aq.y * wv.x; A1.y += aq.y * wv.y; A1.z += aq.y * wv.z; A1.w += aq.y * wv.w;
      A2.x += aq.z * wv.x; A2.y += aq.z * wv.y; A2.z += aq.z * wv.z; A2.w += aq.z * wv.w;
      A3.x += aq.w * wv.x; A3.y += aq.w * wv.y; A3.z += aq.w * wv.z; A3.w += aq.w * wv.w;
    }
    float4 acc[4] = {A0, A1, A2, A3};
#pragma unroll
    for (int pp = 0; pp < 4; ++pp) {
      float4 pe = *(const float4*)&peq[(size_t)(n0 + p4 + pp) * 128 + c4];
      float4 r;
      r.x = acc[pp].x + pe.x; r.y = acc[pp].y + pe.y;
      r.z = acc[pp].z + pe.z; r.w = acc[pp].w + pe.w;
      *(float4*)&sQP[(p4 + pp) * 132 + c4] = r;
    }
  }
  __syncthreads();

  // phase 3: attention. 32 lanes per point, 4 channels per lane. bf16 kv.
  {
    int sub = lane & 31, half = lane >> 5, c4 = sub * 4;
    const unsigned short* Vb = kv16 + (size_t)b * 5 * 65536;
    const float4* gbase = &gtab[(size_t)(b * 5) * NTRI];
    for (int s = 0; s < 4; ++s) {
      int pt = s * 8 + w * 2 + half;
      int n = n0 + pt;
      float4 qp4 = *(const float4*)&sQP[pt * 132 + c4];
      float4 gp[5];
#pragma unroll
      for (int j = 0; j < 5; ++j) gp[j] = gbase[(size_t)j * NTRI + n];
      float4 vst[5];
      float sc[5];
#pragma unroll
      for (int j = 0; j < 5; ++j) {
        int pack = __float_as_int(gp[j].z);
        int x0 = pack & 255, x1 = (pack >> 8) & 255;
        int y0 = (pack >> 16) & 255, y1 = (pack >> 24) & 255;
        float wx = gp[j].x, wy = gp[j].y;
        const unsigned short* r0 = Vb + j * 65536 + y0 * 4096;
        const unsigned short* r1 = Vb + j * 65536 + y1 * 4096;
        int i0 = x0 * 256 + c4, i1 = x1 * 256 + c4;
        uint2 K00 = *(const uint2*)(r0 + i0), K01 = *(const uint2*)(r0 + i1);
        uint2 K10 = *(const uint2*)(r1 + i0), K11 = *(const uint2*)(r1 + i1);
        uint2 V00 = *(const uint2*)(r0 + i0 + 128), V01 = *(const uint2*)(r0 + i1 + 128);
        uint2 V10 = *(const uint2*)(r1 + i0 + 128), V11 = *(const uint2*)(r1 + i1 + 128);
        float w00 = (1.f - wx) * (1.f - wy), w01 = wx * (1.f - wy);
        float w10 = (1.f - wx) * wy, w11 = wx * wy;
        float4 kc, vc;
        kc.x = bflo(K00.x) * w00 + bflo(K01.x) * w01 + bflo(K10.x) * w10 + bflo(K11.x) * w11;
        kc.y = bfhi(K00.x) * w00 + bfhi(K01.x) * w01 + bfhi(K10.x) * w10 + bfhi(K11.x) * w11;
        kc.z = bflo(K00.y) * w00 + bflo(K01.y) * w01 + bflo(K10.y) * w10 + bflo(K11.y) * w11;
        kc.w = bfhi(K00.y) * w00 + bfhi(K01.y) * w01 + bfhi(K10.y) * w10 + bfhi(K11.y) * w11;
        vc.x = bflo(V00.x) * w00 + bflo(V01.x) * w01 + bflo(V10.x) * w10 + bflo(V11.x) * w11;
        vc.y = bfhi(V00.x) * w00 + bfhi(V01.x) * w01 + bfhi(V10.x) * w10 + bfhi(V11.x) * w11;
        vc.z = bflo(V00.y) * w00 + bflo(V01.y) * w01 + bflo(V10.y) * w10 + bflo(V11.y) * w11;
        vc.w = bfhi(V00.y) * w00 + bfhi(V01.y) * w01 + bfhi(V10.y) * w10 + bfhi(V11.y) * w11;
        vst[j] = vc;
        float pa = qp4.x * kc.x + qp4.y * kc.y + qp4.z * kc.z + qp4.w * kc.w;
        pa += __shfl_xor(pa, 1);
        pa += __shfl_xor(pa, 2);   // head = 16 ch = 4 lanes
        sc[j] = pa * 0.25f;
      }
      float mx = fmaxf(fmaxf(fmaxf(sc[0], sc[1]), fmaxf(sc[2], sc[3])), sc[4]);
      float e0 = expf(sc[0] - mx), e1 = expf(sc[1] - mx), e2 = expf(sc[2] - mx);
      float e3 = expf(sc[3] - mx), e4 = expf(sc[4] - mx);
      float inv = 1.0f / (e0 + e1 + e2 + e3 + e4);
      float4 oa;
      oa.x = (e0 * vst[0].x + e1 * vst[1].x + e2 * vst[2].x + e3 * vst[3].x + e4 * vst[4].x) * inv;
      oa.y = (e0 * vst[0].y + e1 * vst[1].y + e2 * vst[2].y + e3 * vst[3].y + e4 * vst[4].y) * inv;
      oa.z = (e0 * vst[0].z + e1 * vst[1].z + e2 * vst[2].z + e3 * vst[3].z + e4 * vst[4].z) * inv;
      oa.w = (e0 * vst[0].w + e1 * vst[1].w + e2 * vst[2].w + e3 * vst[3].w + e4 * vst[4].w) * inv;
      *(float4*)&sO2[pt * 132 + c4] = oa;
    }
  }
  __syncthreads();

  // phase 4: FO[oc][pt] = W2 @ O + b2 (fp32 VALU)
  {
    int oc4 = (t & 15) * 4;
    int pg = t >> 4;  // 16 groups x 2 pts
    float f00 = 0, f01 = 0, f02 = 0, f03 = 0;
    float f10 = 0, f11 = 0, f12 = 0, f13 = 0;
    const float* o0 = &sO2[(pg * 2) * 132];
    const float* o1 = &sO2[(pg * 2 + 1) * 132];
#pragma unroll 8
    for (int cc = 0; cc < 128; ++cc) {
      float4 wv = *(const float4*)&w2t[cc * 64 + oc4];
      float ax = o0[cc], ay = o1[cc];
      f00 += ax * wv.x; f01 += ax * wv.y; f02 += ax * wv.z; f03 += ax * wv.w;
      f10 += ay * wv.x; f11 += ay * wv.y; f12 += ay * wv.z; f13 += ay * wv.w;
    }
    float4 bb = *(const float4*)&b2[oc4];
    int p0 = pg * 2, p1 = pg * 2 + 1;
    sQP[(oc4 + 0) * 33 + p0] = f00 + bb.x; sQP[(oc4 + 0) * 33 + p1] = f10 + bb.x;
    sQP[(oc4 + 1) * 33 + p0] = f01 + bb.y; sQP[(oc4 + 1) * 33 + p1] = f11 + bb.y;
    sQP[(oc4 + 2) * 33 + p0] = f02 + bb.z; sQP[(oc4 + 2) * 33 + p1] = f12 + bb.z;
    sQP[(oc4 + 3) * 33 + p0] = f03 + bb.w; sQP[(oc4 + 3) * 33 + p1] = f13 + bb.w;
  }
  __syncthreads();

  for (int it = 0; it < 8; ++it) {
    int e = it * 256 + t;
    int oc = e >> 5, pt = e & 31;
    outp[(size_t)(b * 64 + oc) * NTRI + n0 + pt] = sQP[oc * 33 + pt];
  }
}

extern "C" void kernel_launch(void* const* d_in, const int* in_sizes, int n_in,
                              void* d_out, int out_size, void* d_ws, size_t ws_size,
                              hipStream_t stream) {
  const float* tri    = (const float*)d_in[0];
  const float* img    = (const float*)d_in[1];
  const float* proj   = (const float*)d_in[2];
  const float* k_w    = (const float*)d_in[4];
  const float* k_b    = (const float*)d_in[5];
  const float* q_w    = (const float*)d_in[6];
  const float* q_b    = (const float*)d_in[7];
  const float* v_w    = (const float*)d_in[8];
  const float* v_b    = (const float*)d_in[9];
  const float* in_w   = (const float*)d_in[10];
  const float* in_b   = (const float*)d_in[11];
  const float* out_w  = (const float*)d_in[12];
  const float* out_b  = (const float*)d_in[13];
  const float* conv_w = (const float*)d_in[14];
  const float* conv_b = (const float*)d_in[15];
  float* ws = (float*)d_ws;
  unsigned short* wTc  = (unsigned short*)(ws + OFF_WT);
  float* pekv = ws + OFF_PEKV;
  float* cqwT = ws + OFF_CQWT;
  float* peq  = ws + OFF_PEQ;
  float* w2t  = ws + OFF_W2T;
  float* b2   = ws + OFF_B2;
  float* inwT = ws + OFF_INWT;
  unsigned short* kv16 = (unsigned short*)(ws + OFF_KVPV);
  float* gtab = ws + OFF_GTAB;
  float* outp = (float*)d_out;

  k_inwT<<<192, 256, 0, stream>>>(in_w, inwT);
  k_pre<<<4097, 256, 0, stream>>>(inwT, k_w, v_w, k_b, v_b, in_b, q_w, q_b,
                                  conv_w, out_w, out_b, conv_b, proj,
                                  wTc, pekv, cqwT, peq, w2t, b2, (float4*)gtab);
  k_kv<<<640, 256, 0, stream>>>(img, wTc, pekv, kv16);
  k_main<<<1536, 256, 0, stream>>>(tri, cqwT, peq, w2t, b2, kv16,
                                   (const float4*)gtab, outp);
}